// Round 9
// baseline (504.828 us; speedup 1.0000x reference)
//
#include <hip/hip_runtime.h>
#include <hip/hip_bf16.h>
#include <stdint.h>

#define NB 4096
#define ND 256
#define NC 32000
#define NCT (NC / 128)   // 250 col-tiles

typedef __bf16 bf16x8 __attribute__((ext_vector_type(8)));
typedef unsigned short u16x8 __attribute__((ext_vector_type(8)));
typedef float  f32x4  __attribute__((ext_vector_type(4)));

__device__ __forceinline__ unsigned short f32_to_bf16(float f) {
  union { float f; uint32_t u; } v; v.f = f;
  uint32_t r = v.u + 0x7fffu + ((v.u >> 16) & 1u);
  return (unsigned short)(r >> 16);
}

// Cast inputs/V to bf16 in workspace; zero loss accumulator.
__global__ void prep_kernel(const float* __restrict__ inA,
                            const float* __restrict__ inV,
                            unsigned short* __restrict__ outA,
                            unsigned short* __restrict__ outV,
                            float* __restrict__ loss) {
  int gid = blockIdx.x * blockDim.x + threadIdx.x;
  int stride = gridDim.x * blockDim.x;
  if (gid == 0) *loss = 0.f;
  const int nA4 = NB * ND / 4;   // 262144
  const int nV4 = NC * ND / 4;   // 2048000
  for (int i = gid; i < nA4 + nV4; i += stride) {
    float4 v = (i < nA4) ? ((const float4*)inA)[i]
                         : ((const float4*)inV)[i - nA4];
    ushort4 o;
    o.x = f32_to_bf16(v.x);
    o.y = f32_to_bf16(v.y);
    o.z = f32_to_bf16(v.z);
    o.w = f32_to_bf16(v.w);
    if (i < nA4) ((ushort4*)outA)[i] = o;
    else         ((ushort4*)outV)[i - nA4] = o;
  }
}

// R5 K-loop (best base): barrier-free, direct global frag loads, swapped
// operands, XCD-swizzled grid, partial-array expsum. PROBE CHANGE (R9):
// tsims is written as BF16 into d_ws (262 MB, aligned 8B stores) instead of
// f32 into d_out. A separate pure-streaming expand kernel produces d_out.
// This isolates "writing d_out" from "the GEMM's write pattern" -- six
// structures all walled at ~2.2 TB/s while fillBuffer wrote d_ws at 6.6.
__global__ void __launch_bounds__(256, 2)
gemm_expsum_kernel(const unsigned short* __restrict__ A,
                   const unsigned short* __restrict__ V,
                   unsigned short* __restrict__ tsims, // bf16 [NB][NC] in ws
                   float* __restrict__ partial) {      // [NCT][NB]
  __shared__ float red[2][128];

  const int b = blockIdx.x;
  const int xcd = b & 7;
  const int s = b >> 3;                     // 0..1023 per XCD
  const int colt = (xcd << 5) + (s & 31);   // 32 col-tiles per XCD, col-fast
  const int rowt = s >> 5;                  // 0..31
  if (colt >= NCT) return;                  // padded tail (colt 250..255)
  const int brow = rowt << 7;
  const int bcol = colt << 7;

  const int tid  = threadIdx.x;
  const int lane = tid & 63;
  const int wave = tid >> 6;
  const int wr   = wave >> 1;
  const int wc   = wave & 1;
  const int c16  = lane & 15;
  const int kq   = lane >> 4;      // 0..3

  const __bf16* Ab = (const __bf16*)A;
  const __bf16* Vb = (const __bf16*)V;
  const __bf16* aBase = Ab + (size_t)(brow + wr * 64 + c16) * ND + kq * 8;
  const __bf16* bBase = Vb + (size_t)(bcol + wc * 64 + c16) * ND + kq * 8;

  f32x4 acc[4][4];   // acc[c][r]: c = V-frag (out cols), r = A-frag (out rows)
#pragma unroll
  for (int c = 0; c < 4; ++c)
#pragma unroll
    for (int r = 0; r < 4; ++r)
      acc[c][r] = (f32x4){0.f, 0.f, 0.f, 0.f};

  bf16x8 a0[4], b0[4], a1[4], b1[4];

#define LOADF(AF, BF, KT)                                                     \
  do {                                                                        \
    _Pragma("unroll")                                                         \
    for (int m = 0; m < 4; ++m)                                               \
      AF[m] = *(const bf16x8*)(aBase + (size_t)m * 16 * ND + (KT) * 32);      \
    _Pragma("unroll")                                                         \
    for (int n = 0; n < 4; ++n)                                               \
      BF[n] = *(const bf16x8*)(bBase + (size_t)n * 16 * ND + (KT) * 32);      \
  } while (0)

#define MFMAALL(AF, BF)                                                       \
  do {                                                                        \
    _Pragma("unroll")                                                         \
    for (int c = 0; c < 4; ++c)                                               \
      _Pragma("unroll")                                                       \
      for (int r = 0; r < 4; ++r)                                             \
        acc[c][r] = __builtin_amdgcn_mfma_f32_16x16x32_bf16(BF[c], AF[r],     \
                                                            acc[c][r], 0, 0, 0); \
  } while (0)

  LOADF(a0, b0, 0);
#pragma unroll
  for (int kt = 0; kt < 8; kt += 2) {
    if (kt + 1 < 8) LOADF(a1, b1, kt + 1);
    MFMAALL(a0, b0);
    if (kt + 2 < 8) LOADF(a0, b0, kt + 2);
    MFMAALL(a1, b1);
  }

  // Epilogue: bf16 8B stores to ws + exp-rowsum into partial (no atomics).
  // acc[c][r] reg q -> tsims[brow+wr*64+r*16+c16][bcol+wc*64+c*16+kq*4+q]
#pragma unroll
  for (int r = 0; r < 4; ++r) {
    const int grow = brow + wr * 64 + r * 16 + c16;
    unsigned short* prow = tsims + (size_t)grow * NC + (bcol + wc * 64 + kq * 4);
    float rsum = 0.f;
#pragma unroll
    for (int c = 0; c < 4; ++c) {
      f32x4 v = acc[c][r];
      rsum += __expf(v[0]) + __expf(v[1]) + __expf(v[2]) + __expf(v[3]);
      ushort4 o;
      o.x = f32_to_bf16(v[0]);
      o.y = f32_to_bf16(v[1]);
      o.z = f32_to_bf16(v[2]);
      o.w = f32_to_bf16(v[3]);
      *(ushort4*)(prow + c * 16) = o;   // 8B aligned
    }
    rsum += __shfl_xor(rsum, 16);
    rsum += __shfl_xor(rsum, 32);
    if (lane < 16) red[wc][wr * 64 + r * 16 + c16] = rsum;
  }
  __syncthreads();
  if (tid < 128)
    partial[(size_t)colt * NB + brow + tid] = red[0][tid] + red[1][tid];
#undef LOADF
#undef MFMAALL
}

// Pure streaming expand: bf16 ws -> f32 d_out (sequential, the same access
// shape as the 6.6 TB/s fillBuffer). d_out dword 0 (loss) written by finalize.
__global__ void expand_kernel(const unsigned short* __restrict__ tsims,
                              float* __restrict__ out0) {  // d_out + 1
  const size_t n8 = (size_t)NB * NC / 8;   // 16,384,000 chunks
  size_t i = (size_t)blockIdx.x * blockDim.x + threadIdx.x;
  const size_t stride = (size_t)gridDim.x * blockDim.x;
  for (; i < n8; i += stride) {
    u16x8 v = ((const u16x8*)tsims)[i];    // aligned 16B
    float* p = out0 + i * 8;
    float4 lo, hi;
    union { uint32_t u; float f; } t;
    t.u = (uint32_t)v[0] << 16; lo.x = t.f;
    t.u = (uint32_t)v[1] << 16; lo.y = t.f;
    t.u = (uint32_t)v[2] << 16; lo.z = t.f;
    t.u = (uint32_t)v[3] << 16; lo.w = t.f;
    t.u = (uint32_t)v[4] << 16; hi.x = t.f;
    t.u = (uint32_t)v[5] << 16; hi.y = t.f;
    t.u = (uint32_t)v[6] << 16; hi.z = t.f;
    t.u = (uint32_t)v[7] << 16; hi.w = t.f;
    *(float4*)(p)     = lo;
    *(float4*)(p + 4) = hi;
  }
}

// loss = mean_r( log(sum_c partial[c][r]) - out[r, targets[r]] )
__global__ void finalize_kernel(const float* __restrict__ partial,
                                const float* __restrict__ out,  // d_out + 1
                                const int* __restrict__ targets,
                                float* __restrict__ loss) {
  int r = blockIdx.x * blockDim.x + threadIdx.x;   // 0..NB-1
  float s = 0.f;
  for (int c = 0; c < NCT; ++c) s += partial[(size_t)c * NB + r];
  float li = logf(s) - out[(size_t)r * NC + targets[r]];
#pragma unroll
  for (int o = 32; o > 0; o >>= 1) li += __shfl_down(li, o);
  __shared__ float wsum[4];
  int lane = threadIdx.x & 63, wv = threadIdx.x >> 6;
  if (lane == 0) wsum[wv] = li;
  __syncthreads();
  if (threadIdx.x == 0) {
    float bs = wsum[0] + wsum[1] + wsum[2] + wsum[3];
    atomicAdd(loss, bs * (1.0f / NB));
  }
}

extern "C" void kernel_launch(void* const* d_in, const int* in_sizes, int n_in,
                              void* d_out, int out_size, void* d_ws, size_t ws_size,
                              hipStream_t stream) {
  const float* inputs  = (const float*)d_in[0];
  const int*   targets = (const int*)d_in[1];
  // d_in[2] indexs, d_in[3] label_to_pairs, d_in[4] all_label_to_clusterid: unused (W_MS = 0)
  const float* V       = (const float*)d_in[5];

  float* loss    = (float*)d_out;          // output 0: scalar loss
  float* outputs = (float*)d_out + 1;      // output 1: [4096][32000]

  char* ws = (char*)d_ws;
  unsigned short* Abf = (unsigned short*)ws;                         // 2 MB
  unsigned short* Vbf = (unsigned short*)(ws + (size_t)NB * ND * 2); // 16.4 MB
  unsigned short* Tbf = (unsigned short*)(ws + (size_t)NB * ND * 2
                                             + (size_t)NC * ND * 2); // 262 MB
  float* partial = (float*)(ws + (size_t)NB * ND * 2 + (size_t)NC * ND * 2
                               + (size_t)NB * NC * 2);               // 4 MB

  hipLaunchKernelGGL(prep_kernel, dim3(2048), dim3(256), 0, stream,
                     inputs, V, Abf, Vbf, loss);
  // grid: 8 XCDs x 1024 (32 col-tiles x 32 row-tiles), col-tiles padded to 256
  hipLaunchKernelGGL(gemm_expsum_kernel, dim3(8 * 1024), dim3(256), 0, stream,
                     Abf, Vbf, Tbf, partial);
  hipLaunchKernelGGL(expand_kernel, dim3(4096), dim3(256), 0, stream,
                     Tbf, outputs);
  hipLaunchKernelGGL(finalize_kernel, dim3(NB / 256), dim3(256), 0, stream,
                     partial, outputs, targets, loss);
}

// Round 10
// 462.747 us; speedup vs baseline: 1.0909x; 1.0909x over previous
//
#include <hip/hip_runtime.h>
#include <hip/hip_bf16.h>
#include <stdint.h>

#define NB 4096
#define ND 256
#define NC 32000
#define WR 32                 // block tile rows
#define WC 640                // block tile cols -> 2560B write span per row
#define NRT (NB / WR)         // 128 row-tiles
#define NCT (NC / WC)         // 50 col-tiles

typedef __bf16 bf16x8 __attribute__((ext_vector_type(8)));
typedef float  f32x4  __attribute__((ext_vector_type(4)));

__device__ __forceinline__ unsigned short f32_to_bf16(float f) {
  union { float f; uint32_t u; } v; v.f = f;
  uint32_t r = v.u + 0x7fffu + ((v.u >> 16) & 1u);
  return (unsigned short)(r >> 16);
}

// Cast inputs/V to bf16 in workspace; zero loss accumulator.
__global__ void prep_kernel(const float* __restrict__ inA,
                            const float* __restrict__ inV,
                            unsigned short* __restrict__ outA,
                            unsigned short* __restrict__ outV,
                            float* __restrict__ loss) {
  int gid = blockIdx.x * blockDim.x + threadIdx.x;
  int stride = gridDim.x * blockDim.x;
  if (gid == 0) *loss = 0.f;
  const int nA4 = NB * ND / 4;   // 262144
  const int nV4 = NC * ND / 4;   // 2048000
  for (int i = gid; i < nA4 + nV4; i += stride) {
    float4 v = (i < nA4) ? ((const float4*)inA)[i]
                         : ((const float4*)inV)[i - nA4];
    ushort4 o;
    o.x = f32_to_bf16(v.x);
    o.y = f32_to_bf16(v.y);
    o.z = f32_to_bf16(v.z);
    o.w = f32_to_bf16(v.w);
    if (i < nA4) ((ushort4*)outA)[i] = o;
    else         ((ushort4*)outV)[i - nA4] = o;
  }
}

// Wide-flat tile GEMM (write-locality probe, done right this time):
// 32x640 block tile, 4 waves SIDE-BY-SIDE (wave = 32 rows x 160 cols,
// acc[2][10] in AGPRs). K-loop = R5's proven alternating-buffer direct-load
// structure (vf 2x10x4=80 + af 2x2x4=16 VGPR -> no R7-style collapse).
// Swapped-operand MFMA -> lane regs = 4 consecutive out cols.
// rowt-fast XCD order: each XCD sweeps its 16 row-tiles within one col-tile
// before advancing -> resident V panels <=4 (1.3MB, L2-hot) and the write
// front is 512 rows x 2560B contiguous patches (5x R5's 512B).
__global__ void __launch_bounds__(256, 2)
gemm_expsum_kernel(const unsigned short* __restrict__ A,
                   const unsigned short* __restrict__ V,
                   float* __restrict__ out,       // d_out + 1
                   float* __restrict__ partial) { // [NCT][NB]
  __shared__ float red[4][32];

  const int b = blockIdx.x;
  const int xcd = b & 7;
  const int i = b >> 3;                    // 0..799 per XCD
  const int colt = i >> 4;                 // 0..49 (slow)
  const int rowt = (xcd << 4) + (i & 15);  // 16 rowts per XCD (fast)
  const int brow = rowt * WR;
  const int bcol = colt * WC;

  const int tid  = threadIdx.x;
  const int lane = tid & 63;
  const int wave = tid >> 6;       // 0..3, side by side
  const int c16  = lane & 15;
  const int kq   = lane >> 4;      // 0..3
  const int vcol = bcol + wave * 160;

  const __bf16* Ab = (const __bf16*)A;
  const __bf16* Vb = (const __bf16*)V;
  const __bf16* aB = Ab + (size_t)(brow + c16) * ND + kq * 8;  // +r*16*ND
  const __bf16* vB = Vb + (size_t)(vcol + c16) * ND + kq * 8;  // +f*16*ND

  f32x4 acc[2][10];   // acc[r][f]: rows r*16+c16, cols f*16+kq*4..+3
#pragma unroll
  for (int r = 0; r < 2; ++r)
#pragma unroll
    for (int f = 0; f < 10; ++f)
      acc[r][f] = (f32x4){0.f, 0.f, 0.f, 0.f};

  bf16x8 af0[2], vf0[10], af1[2], vf1[10];

#define LOADF(AF, VF, KT)                                                     \
  do {                                                                        \
    _Pragma("unroll")                                                         \
    for (int r = 0; r < 2; ++r)                                               \
      AF[r] = *(const bf16x8*)(aB + (size_t)r * 16 * ND + (KT) * 32);         \
    _Pragma("unroll")                                                         \
    for (int f = 0; f < 10; ++f)                                              \
      VF[f] = *(const bf16x8*)(vB + (size_t)f * 16 * ND + (KT) * 32);         \
  } while (0)

#define MFMAALL(AF, VF)                                                       \
  do {                                                                        \
    _Pragma("unroll")                                                         \
    for (int f = 0; f < 10; ++f)                                              \
      _Pragma("unroll")                                                       \
      for (int r = 0; r < 2; ++r)                                             \
        acc[r][f] = __builtin_amdgcn_mfma_f32_16x16x32_bf16(VF[f], AF[r],     \
                                                            acc[r][f], 0, 0, 0); \
  } while (0)

  LOADF(af0, vf0, 0);
#pragma unroll
  for (int kt = 0; kt < 8; kt += 2) {
    if (kt + 1 < 8) LOADF(af1, vf1, kt + 1);
    MFMAALL(af0, vf0);
    if (kt + 2 < 8) LOADF(af0, vf0, kt + 2);
    MFMAALL(af1, vf1);
  }

  // Epilogue: direct f32x4 stores + fused exp-rowsum (no atomics).
  // acc[r][f] reg q -> out[brow+r*16+c16][vcol + f*16 + kq*4 + q]
  float s0 = 0.f, s1 = 0.f;
#pragma unroll
  for (int r = 0; r < 2; ++r) {
    float* prow = out + (size_t)(brow + r * 16 + c16) * NC + vcol + kq * 4;
    float s = 0.f;
#pragma unroll
    for (int f = 0; f < 10; ++f) {
      f32x4 v = acc[r][f];
      *(f32x4*)(prow + f * 16) = v;
      s += __expf(v[0]) + __expf(v[1]) + __expf(v[2]) + __expf(v[3]);
    }
    if (r == 0) s0 = s; else s1 = s;
  }
  s0 += __shfl_xor(s0, 16);
  s0 += __shfl_xor(s0, 32);
  s1 += __shfl_xor(s1, 16);
  s1 += __shfl_xor(s1, 32);
  if (lane < 16) {
    red[wave][c16]      = s0;
    red[wave][16 + c16] = s1;
  }
  __syncthreads();
  if (tid < 32)
    partial[(size_t)colt * NB + brow + tid] =
        red[0][tid] + red[1][tid] + red[2][tid] + red[3][tid];
#undef LOADF
#undef MFMAALL
}

// loss = mean_r( log(sum_c partial[c][r]) - out[r, targets[r]] )
__global__ void finalize_kernel(const float* __restrict__ partial,
                                const float* __restrict__ out,  // d_out + 1
                                const int* __restrict__ targets,
                                float* __restrict__ loss) {
  int r = blockIdx.x * blockDim.x + threadIdx.x;   // 0..NB-1
  float s = 0.f;
#pragma unroll 5
  for (int c = 0; c < NCT; ++c) s += partial[(size_t)c * NB + r];
  float li = logf(s) - out[(size_t)r * NC + targets[r]];
#pragma unroll
  for (int o = 32; o > 0; o >>= 1) li += __shfl_down(li, o);
  __shared__ float wsum[4];
  int lane = threadIdx.x & 63, wv = threadIdx.x >> 6;
  if (lane == 0) wsum[wv] = li;
  __syncthreads();
  if (threadIdx.x == 0) {
    float bs = wsum[0] + wsum[1] + wsum[2] + wsum[3];
    atomicAdd(loss, bs * (1.0f / NB));
  }
}

extern "C" void kernel_launch(void* const* d_in, const int* in_sizes, int n_in,
                              void* d_out, int out_size, void* d_ws, size_t ws_size,
                              hipStream_t stream) {
  const float* inputs  = (const float*)d_in[0];
  const int*   targets = (const int*)d_in[1];
  // d_in[2] indexs, d_in[3] label_to_pairs, d_in[4] all_label_to_clusterid: unused (W_MS = 0)
  const float* V       = (const float*)d_in[5];

  float* loss    = (float*)d_out;          // output 0: scalar loss
  float* outputs = (float*)d_out + 1;      // output 1: [4096][32000]

  char* ws = (char*)d_ws;
  unsigned short* Abf = (unsigned short*)ws;                              // 2 MB
  unsigned short* Vbf = (unsigned short*)(ws + (size_t)NB * ND * 2);      // 16.4 MB
  float* partial = (float*)(ws + (size_t)NB * ND * 2 + (size_t)NC * ND * 2); // 800 KB

  hipLaunchKernelGGL(prep_kernel, dim3(2048), dim3(256), 0, stream,
                     inputs, V, Abf, Vbf, loss);
  // grid: 8 XCDs x 800 (50 col-tiles x 16 row-tiles, rowt-fast)
  hipLaunchKernelGGL(gemm_expsum_kernel, dim3(8 * 800), dim3(256), 0, stream,
                     Abf, Vbf, outputs, partial);
  hipLaunchKernelGGL(finalize_kernel, dim3(NB / 256), dim3(256), 0, stream,
                     partial, outputs, targets, loss);
}